// Round 5
// baseline (569.133 us; speedup 1.0000x reference)
//
#include <hip/hip_runtime.h>
#include <hip/hip_bf16.h>

#define B_ 8
#define N_ 1024
#define D_ 1024
#define H_ 16
#define FF_ 4096
#define TOK_ (B_*N_)

typedef __attribute__((ext_vector_type(8))) short bf16x8;
typedef __attribute__((ext_vector_type(4))) float f32x4;

typedef const __attribute__((address_space(1))) void* gc_ptr;
typedef __attribute__((address_space(3))) void* lp_ptr;

// float -> bf16 bits, round-to-nearest-even (values are finite; no NaN path needed)
__device__ __forceinline__ short f2bf(float f) {
    unsigned u = __builtin_bit_cast(unsigned, f);
    u = (u + 0x7FFFu + ((u >> 16) & 1u)) >> 16;
    return (short)u;
}

// ---------------------------------------------------------------------------
// fp32 -> bf16 convert (weights), 4 elements/thread
// ---------------------------------------------------------------------------
__global__ __launch_bounds__(256)
void cvt_bf16(const float* __restrict__ in, short* __restrict__ outp) {
    const size_t i = ((size_t)blockIdx.x * 256 + threadIdx.x) * 4;
    const float4 v = *(const float4*)(in + i);
    short4 o;
    o.x = f2bf(v.x); o.y = f2bf(v.y); o.z = f2bf(v.z); o.w = f2bf(v.w);
    *(short4*)(outp + i) = o;
}

// ---------------------------------------------------------------------------
// LayerNorm over D=1024: one block per row, 256 threads, 4 floats each.
// Writes fp32 (residual path) and bf16 (GEMM input).
// ---------------------------------------------------------------------------
__global__ __launch_bounds__(256)
void ln_kernel(const float* __restrict__ in, const float* __restrict__ w,
               const float* __restrict__ bi, float* __restrict__ o32,
               short* __restrict__ obf) {
    const int row = blockIdx.x;
    const int tid = threadIdx.x;
    const float4 v = ((const float4*)(in + (size_t)row * D_))[tid];
    float s = v.x + v.y + v.z + v.w;
    float q = v.x * v.x + v.y * v.y + v.z * v.z + v.w * v.w;
#pragma unroll
    for (int off = 1; off < 64; off <<= 1) {
        s += __shfl_xor(s, off);
        q += __shfl_xor(q, off);
    }
    __shared__ float ss[4], sq[4];
    const int wave = tid >> 6, lane = tid & 63;
    if (lane == 0) { ss[wave] = s; sq[wave] = q; }
    __syncthreads();
    s = ss[0] + ss[1] + ss[2] + ss[3];
    q = sq[0] + sq[1] + sq[2] + sq[3];
    const float mu = s * (1.f / D_);
    const float var = q * (1.f / D_) - mu * mu;
    const float rs = rsqrtf(var + 1e-5f);
    const float4 wv = ((const float4*)w)[tid];
    const float4 bv = ((const float4*)bi)[tid];
    float4 o;
    o.x = (v.x - mu) * rs * wv.x + bv.x;
    o.y = (v.y - mu) * rs * wv.y + bv.y;
    o.z = (v.z - mu) * rs * wv.z + bv.z;
    o.w = (v.w - mu) * rs * wv.w + bv.w;
    ((float4*)(o32 + (size_t)row * D_))[tid] = o;
    short4 ob;
    ob.x = f2bf(o.x); ob.y = f2bf(o.y); ob.z = f2bf(o.z); ob.w = f2bf(o.w);
    *(short4*)(obf + (size_t)row * D_ + tid * 4) = ob;
}

// ---------------------------------------------------------------------------
// GEMM: C[M,Nc] = A[M,K] @ Bw[Nc,K]^T  (both bf16, K-contiguous)
// 128x128 tile, BK=32, 4 waves each owning 64x64 (4x4 of 16x16x32 MFMA).
// v2: DOUBLE-BUFFERED staging, ONE barrier/iter, stage(t+1) issued right
// after the barrier publishing tile t (prefetch distance = full compute
// phase) — same pattern that fixed attn in R4. Plus supertile swizzle
// (col fastest within 8-row bands) for per-XCD L2 locality.
// MODE 0: scatter q,k -> [B,H,N,64]; v -> TRANSPOSED [B,H,64,N]
// MODE 1: out_f32 = acc + bias[col] + res[row,col]
// MODE 2: out_bf16 = gelu_exact(acc + bias[col])
// ---------------------------------------------------------------------------
template<int MODE>
__global__ __launch_bounds__(256, 2)
void gemm_bt(const short* __restrict__ A, const short* __restrict__ Bw,
             const float* __restrict__ bias, const float* __restrict__ res,
             void* __restrict__ outp, int M, int Nc, int K) {
    const int tid  = threadIdx.x;
    const int wave = tid >> 6;
    const int lane = tid & 63;
    const int m16  = lane & 15;
    const int quad = lane >> 4;
    const int wrow = (wave >> 1) * 64;
    const int wcol = (wave & 1) * 64;

    // supertile swizzle: within a band of 8 row-tiles, col-tile varies fastest
    const int gx = gridDim.x;
    const int lin = blockIdx.y * gx + blockIdx.x;
    const int bandSz = gx * 8;
    const int band = lin / bandSz;
    const int rem  = lin - band * bandSz;
    const int rowBase = (band * 8 + rem / gx) * 128;
    const int colBase = (rem % gx) * 128;

    __shared__ short sA[2][128 * 32];
    __shared__ short sB[2][128 * 32];

    f32x4 acc[4][4];
#pragma unroll
    for (int i = 0; i < 4; ++i)
#pragma unroll
        for (int j = 0; j < 4; ++j)
            acc[i][j] = {0.f, 0.f, 0.f, 0.f};

    const int r16 = lane >> 2;   // row within 16-row staging group
    const int c4  = lane & 3;    // 16B chunk within 64B row

    auto stage = [&](int t) {
        const int kt = t * 32;
        short* dA = sA[t & 1];
        short* dB = sB[t & 1];
#pragma unroll
        for (int rep = 0; rep < 2; ++rep) {
            const int tr = rep * 64 + wave * 16;
            const short* ga = A  + (size_t)(rowBase + tr + r16) * K + kt + c4 * 8;
            const short* gb = Bw + (size_t)(colBase + tr + r16) * K + kt + c4 * 8;
            __builtin_amdgcn_global_load_lds((gc_ptr)ga, (lp_ptr)(dA + tr * 32), 16, 0, 0);
            __builtin_amdgcn_global_load_lds((gc_ptr)gb, (lp_ptr)(dB + tr * 32), 16, 0, 0);
        }
    };

    const int T = K >> 5;
    stage(0);
    for (int t = 0; t < T; ++t) {
        __syncthreads();             // implicit vmcnt drain publishes tile t
        if (t + 1 < T) stage(t + 1); // prefetch next tile into other buffer
        const short* cA = sA[t & 1];
        const short* cB = sB[t & 1];

        bf16x8 af[4], bfr[4];
#pragma unroll
        for (int i = 0; i < 4; ++i)
            af[i] = *(const bf16x8*)(cA + (wrow + i * 16 + m16) * 32 + quad * 8);
#pragma unroll
        for (int j = 0; j < 4; ++j)
            bfr[j] = *(const bf16x8*)(cB + (wcol + j * 16 + m16) * 32 + quad * 8);
#pragma unroll
        for (int i = 0; i < 4; ++i)
#pragma unroll
            for (int j = 0; j < 4; ++j)
                acc[i][j] = __builtin_amdgcn_mfma_f32_16x16x32_bf16(af[i], bfr[j], acc[i][j], 0, 0, 0);
    }

    // epilogue: C/D layout col = lane&15, row = quad*4 + r  (m89-verified)
#pragma unroll
    for (int i = 0; i < 4; ++i) {
#pragma unroll
        for (int j = 0; j < 4; ++j) {
            const int col = colBase + wcol + j * 16 + m16;
#pragma unroll
            for (int r = 0; r < 4; ++r) {
                const int row = rowBase + wrow + i * 16 + quad * 4 + r;
                const float val = acc[i][j][r];
                if (MODE == 0) {
                    const int ci = col >> 10, hh = (col >> 6) & 15, dd = col & 63;
                    const int bb = row >> 10, nn = row & 1023;
                    size_t idx;
                    if (ci == 2)   // V transposed: [b,h,dh,N]
                        idx = (size_t)2 * ((size_t)TOK_ * 1024) +
                              ((size_t)((bb * H_ + hh) * 64 + dd)) * N_ + nn;
                    else
                        idx = (size_t)ci * ((size_t)TOK_ * 1024) +
                              ((size_t)((bb * H_ + hh) * N_ + nn)) * 64 + dd;
                    ((short*)outp)[idx] = f2bf(val);
                } else if (MODE == 1) {
                    ((float*)outp)[(size_t)row * Nc + col] =
                        val + bias[col] + res[(size_t)row * Nc + col];
                } else {
                    const float t = val + bias[col];
                    const float g = 0.5f * t * (1.f + erff(t * 0.70710678118654752f));
                    ((short*)outp)[(size_t)row * Nc + col] = f2bf(g);
                }
            }
        }
    }
}

// ---------------------------------------------------------------------------
// Flash attention v3: block = (64 q-rows, h, b), 4 waves x 16 q-rows.
// KT=64 keys/tile, double-buffered K/V staged via global_load_lds (width 16),
// ONE barrier per tile; staging for tile t+1 issued right after the barrier
// that publishes tile t. No-max softmax (masked -> exp==0 exact);
// row-sum accumulated in registers, reduced once at the end.
// ---------------------------------------------------------------------------
__global__ __launch_bounds__(256, 4)
void attn_kernel(const short* __restrict__ q, const short* __restrict__ k,
                 const short* __restrict__ vT, const int* __restrict__ ids,
                 short* __restrict__ outp) {
    const int tid  = threadIdx.x;
    const int wave = tid >> 6;
    const int lane = tid & 63;
    const int m    = lane & 15;
    const int quad = lane >> 4;
    const int b  = blockIdx.z;
    const int h  = blockIdx.y;
    const int q0 = blockIdx.x * 64;
    const size_t bh = ((size_t)b * H_ + h) * N_;

    // K half-tiles: [dh-half][key 0..63][32 shorts]; V half-tiles: [key-half][dh 0..63][32 shorts]
    __shared__ short Kb[2][4096];
    __shared__ short Vb[2][4096];
    __shared__ short Pl[4][16 * 40];   // per-wave P tile [qrow][32 keys + pad]

    const short* kbase  = k  + bh * 64;
    const short* vtbase = vT + bh * 64;   // [dh][N] for this (b,h)
    const int* idrow = ids + b * N_;

    // Q A-frags (two dh-chunks of 32)
    bf16x8 aq0, aq1;
    {
        const short* qp = q + (bh + q0 + wave * 16 + m) * 64;
        aq0 = *(const bf16x8*)(qp + quad * 8);
        aq1 = *(const bf16x8*)(qp + 32 + quad * 8);
    }

    const int l4 = lane >> 2, c3 = lane & 3;   // staging lane split: 16 rows x 4 chunks

    auto stage = [&](int t) {
        short* Kd = Kb[t & 1];
        short* Vd = Vb[t & 1];
        const int kt = t * 64;
        const int keyrow = 16 * wave + l4;      // key (for K) / dh (for V), 0..63
#pragma unroll
        for (int hh = 0; hh < 2; ++hh) {        // K: dh-half hh
            const short* gk = kbase + (size_t)(kt + keyrow) * 64 + hh * 32 + c3 * 8;
            __builtin_amdgcn_global_load_lds((gc_ptr)gk,
                (lp_ptr)(Kd + hh * 2048 + 512 * wave + lane * 8), 16, 0, 0);
        }
#pragma unroll
        for (int g = 0; g < 2; ++g) {           // V: key-half g
            const short* gv = vtbase + (size_t)keyrow * N_ + kt + g * 32 + c3 * 8;
            __builtin_amdgcn_global_load_lds((gc_ptr)gv,
                (lp_ptr)(Vd + g * 2048 + 512 * wave + lane * 8), 16, 0, 0);
        }
    };

    float plocal[4] = {0.f, 0.f, 0.f, 0.f};
    f32x4 o[4];
#pragma unroll
    for (int j = 0; j < 4; ++j) o[j] = {0.f, 0.f, 0.f, 0.f};

    short* pw = Pl[wave];

    stage(0);
    for (int t = 0; t < 16; ++t) {
        __syncthreads();                // implicit vmcnt drain publishes tile t
        if (t < 15) stage(t + 1);       // prefetch next tile into other buffer
        const short* Ks = Kb[t & 1];
        const short* Vs = Vb[t & 1];
        const int kt = t * 64;
#pragma unroll
        for (int g = 0; g < 2; ++g) {   // two 32-key subgroups
            const float msk0 = -1e9f * (float)idrow[kt + g * 32 + m];
            const float msk1 = -1e9f * (float)idrow[kt + g * 32 + 16 + m];
            const bf16x8 b00 = *(const bf16x8*)(Ks + (g * 32 + m) * 32 + quad * 8);
            const bf16x8 b01 = *(const bf16x8*)(Ks + 2048 + (g * 32 + m) * 32 + quad * 8);
            const bf16x8 b10 = *(const bf16x8*)(Ks + (g * 32 + 16 + m) * 32 + quad * 8);
            const bf16x8 b11 = *(const bf16x8*)(Ks + 2048 + (g * 32 + 16 + m) * 32 + quad * 8);
            f32x4 s0 = {0.f, 0.f, 0.f, 0.f}, s1 = {0.f, 0.f, 0.f, 0.f};
            s0 = __builtin_amdgcn_mfma_f32_16x16x32_bf16(aq0, b00, s0, 0, 0, 0);
            s0 = __builtin_amdgcn_mfma_f32_16x16x32_bf16(aq1, b01, s0, 0, 0, 0);
            s1 = __builtin_amdgcn_mfma_f32_16x16x32_bf16(aq0, b10, s1, 0, 0, 0);
            s1 = __builtin_amdgcn_mfma_f32_16x16x32_bf16(aq1, b11, s1, 0, 0, 0);
#pragma unroll
            for (int r = 0; r < 4; ++r) {
                const float p0 = __expf((s0[r] + msk0) * 0.125f);
                const float p1 = __expf((s1[r] + msk1) * 0.125f);
                plocal[r] += p0 + p1;
                pw[(quad * 4 + r) * 40 + m]      = f2bf(p0);
                pw[(quad * 4 + r) * 40 + 16 + m] = f2bf(p1);
            }
            // same-wave LDS round-trip (C-layout -> A-layout), no barrier needed
            const bf16x8 pa = *(const bf16x8*)(pw + m * 40 + quad * 8);
#pragma unroll
            for (int j = 0; j < 4; ++j) {
                const bf16x8 bv = *(const bf16x8*)(Vs + g * 2048 + (j * 16 + m) * 32 + quad * 8);
                o[j] = __builtin_amdgcn_mfma_f32_16x16x32_bf16(pa, bv, o[j], 0, 0, 0);
            }
        }
    }

    // single end-of-kernel row-sum reduce, then write O: out[b, n, h*64 + dh]
#pragma unroll
    for (int r = 0; r < 4; ++r) {
        float su = plocal[r];
        su += __shfl_xor(su, 1);
        su += __shfl_xor(su, 2);
        su += __shfl_xor(su, 4);
        su += __shfl_xor(su, 8);
        const float inv = 1.f / su;
        const int n = q0 + wave * 16 + quad * 4 + r;
        short* op = outp + ((size_t)(b * N_ + n)) * D_ + h * 64 + m;
#pragma unroll
        for (int j = 0; j < 4; ++j)
            op[j * 16] = f2bf(o[j][r] * inv);
    }
}

// ---------------------------------------------------------------------------
extern "C" void kernel_launch(void* const* d_in, const int* in_sizes, int n_in,
                              void* d_out, int out_size, void* d_ws, size_t ws_size,
                              hipStream_t stream) {
    const float* x   = (const float*)d_in[0];
    const int*   ids = (const int*)d_in[1];
    const float* n1w = (const float*)d_in[2];
    const float* n1b = (const float*)d_in[3];
    const float* win = (const float*)d_in[4];
    const float* wout= (const float*)d_in[5];
    const float* bout= (const float*)d_in[6];
    const float* n2w = (const float*)d_in[7];
    const float* n2b = (const float*)d_in[8];
    const float* w1  = (const float*)d_in[9];
    const float* b1  = (const float*)d_in[10];
    const float* w2  = (const float*)d_in[11];
    const float* b2  = (const float*)d_in[12];
    float* out = (float*)d_out;

    char* ws = (char*)d_ws;
    size_t off = 0;
    auto alloc = [&](size_t bytes) {
        char* p = ws + off;
        off += (bytes + 255) & ~(size_t)255;
        return p;
    };
    short* wq_b = (short*)alloc((size_t)3 * D_ * D_ * 2);       // proj_in bf16
    short* wo_b = (short*)alloc((size_t)D_ * D_ * 2);           // proj_out bf16
    short* w1_b = (short*)alloc((size_t)FF_ * D_ * 2);          // lin1 bf16
    short* w2_b = (short*)alloc((size_t)D_ * FF_ * 2);          // lin2 bf16
    float* xn32 = (float*)alloc((size_t)TOK_ * D_ * 4);         // LN1 out fp32
    short* xnb  = (short*)alloc((size_t)TOK_ * D_ * 2);         // LN1 out bf16
    short* qkv  = (short*)alloc((size_t)3 * TOK_ * D_ * 2);     // q,k [B,H,N,64]; vT [B,H,64,N]
    float* x2f  = (float*)alloc((size_t)TOK_ * D_ * 4);         // LN2 out fp32
    short* hbuf = (short*)alloc((size_t)TOK_ * FF_ * 2);        // gelu(lin1) bf16
    // aliases (lifetimes disjoint in stream order):
    short* attno = xnb;          // attention output bf16 (xn_bf16 dead after QKV gemm)
    float* x1f   = (float*)qkv;  // x1 fp32 (qkv dead after attention)
    short* x2b   = xnb;          // LN2 bf16 (attno dead after proj_out gemm)

    // 1) weights -> bf16
    cvt_bf16<<<3 * D_ * D_ / 1024, 256, 0, stream>>>(win, wq_b);
    cvt_bf16<<<D_ * D_ / 1024, 256, 0, stream>>>(wout, wo_b);
    cvt_bf16<<<FF_ * D_ / 1024, 256, 0, stream>>>(w1, w1_b);
    cvt_bf16<<<FF_ * D_ / 1024, 256, 0, stream>>>(w2, w2_b);
    // 2) LN1
    ln_kernel<<<TOK_, 256, 0, stream>>>(x, n1w, n1b, xn32, xnb);
    // 3) QKV projection (scatter epilogue, V transposed)
    gemm_bt<0><<<dim3(3 * D_ / 128, TOK_ / 128), 256, 0, stream>>>(
        xnb, wq_b, nullptr, nullptr, qkv, TOK_, 3 * D_, D_);
    // 4) attention
    attn_kernel<<<dim3(N_ / 64, H_, B_), 256, 0, stream>>>(
        qkv, qkv + (size_t)TOK_ * D_, qkv + (size_t)2 * TOK_ * D_, ids, attno);
    // 5) out projection + bias + residual(xn) -> x1 fp32
    gemm_bt<1><<<dim3(D_ / 128, TOK_ / 128), 256, 0, stream>>>(
        attno, wo_b, bout, xn32, x1f, TOK_, D_, D_);
    // 6) LN2
    ln_kernel<<<TOK_, 256, 0, stream>>>(x1f, n2w, n2b, x2f, x2b);
    // 7) lin1 + bias + GELU -> h bf16
    gemm_bt<2><<<dim3(FF_ / 128, TOK_ / 128), 256, 0, stream>>>(
        x2b, w1_b, b1, nullptr, hbuf, TOK_, FF_, D_);
    // 8) lin2 + bias + residual(x2) -> out fp32
    gemm_bt<1><<<dim3(D_ / 128, TOK_ / 128), 256, 0, stream>>>(
        hbuf, w2_b, b2, x2f, out, TOK_, D_, FF_);
}

// Round 6
// 550.594 us; speedup vs baseline: 1.0337x; 1.0337x over previous
//
#include <hip/hip_runtime.h>
#include <hip/hip_bf16.h>

#define B_ 8
#define N_ 1024
#define D_ 1024
#define H_ 16
#define FF_ 4096
#define TOK_ (B_*N_)

typedef __attribute__((ext_vector_type(8))) short bf16x8;
typedef __attribute__((ext_vector_type(4))) float f32x4;

typedef const __attribute__((address_space(1))) void* gc_ptr;
typedef __attribute__((address_space(3))) void* lp_ptr;

// float -> bf16 bits, round-to-nearest-even (values are finite; no NaN path needed)
__device__ __forceinline__ short f2bf(float f) {
    unsigned u = __builtin_bit_cast(unsigned, f);
    u = (u + 0x7FFFu + ((u >> 16) & 1u)) >> 16;
    return (short)u;
}

// ---------------------------------------------------------------------------
// fp32 -> bf16 convert (weights), 4 elements/thread
// ---------------------------------------------------------------------------
__global__ __launch_bounds__(256)
void cvt_bf16(const float* __restrict__ in, short* __restrict__ outp) {
    const size_t i = ((size_t)blockIdx.x * 256 + threadIdx.x) * 4;
    const float4 v = *(const float4*)(in + i);
    short4 o;
    o.x = f2bf(v.x); o.y = f2bf(v.y); o.z = f2bf(v.z); o.w = f2bf(v.w);
    *(short4*)(outp + i) = o;
}

// ---------------------------------------------------------------------------
// LayerNorm over D=1024: one block per row, 256 threads, 4 floats each.
// Writes fp32 (residual path) and bf16 (GEMM input).
// ---------------------------------------------------------------------------
__global__ __launch_bounds__(256)
void ln_kernel(const float* __restrict__ in, const float* __restrict__ w,
               const float* __restrict__ bi, float* __restrict__ o32,
               short* __restrict__ obf) {
    const int row = blockIdx.x;
    const int tid = threadIdx.x;
    const float4 v = ((const float4*)(in + (size_t)row * D_))[tid];
    float s = v.x + v.y + v.z + v.w;
    float q = v.x * v.x + v.y * v.y + v.z * v.z + v.w * v.w;
#pragma unroll
    for (int off = 1; off < 64; off <<= 1) {
        s += __shfl_xor(s, off);
        q += __shfl_xor(q, off);
    }
    __shared__ float ss[4], sq[4];
    const int wave = tid >> 6, lane = tid & 63;
    if (lane == 0) { ss[wave] = s; sq[wave] = q; }
    __syncthreads();
    s = ss[0] + ss[1] + ss[2] + ss[3];
    q = sq[0] + sq[1] + sq[2] + sq[3];
    const float mu = s * (1.f / D_);
    const float var = q * (1.f / D_) - mu * mu;
    const float rs = rsqrtf(var + 1e-5f);
    const float4 wv = ((const float4*)w)[tid];
    const float4 bv = ((const float4*)bi)[tid];
    float4 o;
    o.x = (v.x - mu) * rs * wv.x + bv.x;
    o.y = (v.y - mu) * rs * wv.y + bv.y;
    o.z = (v.z - mu) * rs * wv.z + bv.z;
    o.w = (v.w - mu) * rs * wv.w + bv.w;
    ((float4*)(o32 + (size_t)row * D_))[tid] = o;
    short4 ob;
    ob.x = f2bf(o.x); ob.y = f2bf(o.y); ob.z = f2bf(o.z); ob.w = f2bf(o.w);
    *(short4*)(obf + (size_t)row * D_ + tid * 4) = ob;
}

// ---------------------------------------------------------------------------
// GEMM: C[M,Nc] = A[M,K] @ Bw[Nc,K]^T  (both bf16, K-contiguous)
// 128x128 tile, BK=32, 4 waves each owning 64x64 (4x4 of 16x16x32 MFMA).
// Double-buffered global_load_lds staging, one barrier/iter.
// v3: 1D grid + XCD-PINNED tile map: xcd = lin&7 (round-robin heuristic);
// XCD x owns all row-tiles r ≡ x (mod 8), col-major within the XCD, so
// every A-stripe's col-sharers live on ONE non-coherent L2 -> A fetched
// once device-wide; resident window per XCD = 8 rows x 8 cols (~4MB) fits L2.
// MODE 0: scatter q,k -> [B,H,N,64]; v -> TRANSPOSED [B,H,64,N]
// MODE 1: out_f32 = acc + bias[col] + res[row,col]
// MODE 2: out_bf16 = gelu_exact(acc + bias[col])
// ---------------------------------------------------------------------------
template<int MODE>
__global__ __launch_bounds__(256, 2)
void gemm_bt(const short* __restrict__ A, const short* __restrict__ Bw,
             const float* __restrict__ bias, const float* __restrict__ res,
             void* __restrict__ outp, int M, int Nc, int K) {
    const int tid  = threadIdx.x;
    const int wave = tid >> 6;
    const int lane = tid & 63;
    const int m16  = lane & 15;
    const int quad = lane >> 4;
    const int wrow = (wave >> 1) * 64;
    const int wcol = (wave & 1) * 64;

    // XCD-pinned decode (requires M/128 % 8 == 0 — true for all calls: gy=64)
    const int gy = M >> 7;             // row-tiles
    const int rowsPerX = gy >> 3;      // row-tiles per XCD
    const int lin  = blockIdx.x;
    const int xcd  = lin & 7;
    const int loc  = lin >> 3;
    const int rowL = loc % rowsPerX;
    const int colT = loc / rowsPerX;
    const int rowBase = (rowL * 8 + xcd) * 128;
    const int colBase = colT * 128;

    __shared__ short sA[2][128 * 32];
    __shared__ short sB[2][128 * 32];

    f32x4 acc[4][4];
#pragma unroll
    for (int i = 0; i < 4; ++i)
#pragma unroll
        for (int j = 0; j < 4; ++j)
            acc[i][j] = {0.f, 0.f, 0.f, 0.f};

    const int r16 = lane >> 2;   // row within 16-row staging group
    const int c4  = lane & 3;    // 16B chunk within 64B row

    auto stage = [&](int t) {
        const int kt = t * 32;
        short* dA = sA[t & 1];
        short* dB = sB[t & 1];
#pragma unroll
        for (int rep = 0; rep < 2; ++rep) {
            const int tr = rep * 64 + wave * 16;
            const short* ga = A  + (size_t)(rowBase + tr + r16) * K + kt + c4 * 8;
            const short* gb = Bw + (size_t)(colBase + tr + r16) * K + kt + c4 * 8;
            __builtin_amdgcn_global_load_lds((gc_ptr)ga, (lp_ptr)(dA + tr * 32), 16, 0, 0);
            __builtin_amdgcn_global_load_lds((gc_ptr)gb, (lp_ptr)(dB + tr * 32), 16, 0, 0);
        }
    };

    const int T = K >> 5;
    stage(0);
    for (int t = 0; t < T; ++t) {
        __syncthreads();             // implicit vmcnt drain publishes tile t
        if (t + 1 < T) stage(t + 1); // prefetch next tile into other buffer
        const short* cA = sA[t & 1];
        const short* cB = sB[t & 1];

        bf16x8 af[4], bfr[4];
#pragma unroll
        for (int i = 0; i < 4; ++i)
            af[i] = *(const bf16x8*)(cA + (wrow + i * 16 + m16) * 32 + quad * 8);
#pragma unroll
        for (int j = 0; j < 4; ++j)
            bfr[j] = *(const bf16x8*)(cB + (wcol + j * 16 + m16) * 32 + quad * 8);
#pragma unroll
        for (int i = 0; i < 4; ++i)
#pragma unroll
            for (int j = 0; j < 4; ++j)
                acc[i][j] = __builtin_amdgcn_mfma_f32_16x16x32_bf16(af[i], bfr[j], acc[i][j], 0, 0, 0);
    }

    // epilogue: C/D layout col = lane&15, row = quad*4 + r  (m89-verified)
#pragma unroll
    for (int i = 0; i < 4; ++i) {
#pragma unroll
        for (int j = 0; j < 4; ++j) {
            const int col = colBase + wcol + j * 16 + m16;
#pragma unroll
            for (int r = 0; r < 4; ++r) {
                const int row = rowBase + wrow + i * 16 + quad * 4 + r;
                const float val = acc[i][j][r];
                if (MODE == 0) {
                    const int ci = col >> 10, hh = (col >> 6) & 15, dd = col & 63;
                    const int bb = row >> 10, nn = row & 1023;
                    size_t idx;
                    if (ci == 2)   // V transposed: [b,h,dh,N]
                        idx = (size_t)2 * ((size_t)TOK_ * 1024) +
                              ((size_t)((bb * H_ + hh) * 64 + dd)) * N_ + nn;
                    else
                        idx = (size_t)ci * ((size_t)TOK_ * 1024) +
                              ((size_t)((bb * H_ + hh) * N_ + nn)) * 64 + dd;
                    ((short*)outp)[idx] = f2bf(val);
                } else if (MODE == 1) {
                    ((float*)outp)[(size_t)row * Nc + col] =
                        val + bias[col] + res[(size_t)row * Nc + col];
                } else {
                    const float t = val + bias[col];
                    const float g = 0.5f * t * (1.f + erff(t * 0.70710678118654752f));
                    ((short*)outp)[(size_t)row * Nc + col] = f2bf(g);
                }
            }
        }
    }
}

// ---------------------------------------------------------------------------
// Flash attention v4: 1D grid, XCD-pinned: lin = qb*128 + (b*16+h), so all
// 16 q-blocks of one head land on one XCD (lin%8 = head%8) -> each head's
// K/V (256KB) fetched by a single L2. Block = 64 q-rows, 4 waves x 16 rows.
// KT=64 double-buffered K/V via global_load_lds; one barrier/tile.
// No-max softmax (masked -> exp==0 exact); row-sum reduced once at end.
// ---------------------------------------------------------------------------
__global__ __launch_bounds__(256, 4)
void attn_kernel(const short* __restrict__ q, const short* __restrict__ k,
                 const short* __restrict__ vT, const int* __restrict__ ids,
                 short* __restrict__ outp) {
    const int tid  = threadIdx.x;
    const int wave = tid >> 6;
    const int lane = tid & 63;
    const int m    = lane & 15;
    const int quad = lane >> 4;
    const int lin  = blockIdx.x;
    const int qb   = lin >> 7;          // 16 q-blocks
    const int bhid = lin & 127;         // b*16+h
    const int b  = bhid >> 4;
    const int h  = bhid & 15;
    const int q0 = qb * 64;
    const size_t bh = ((size_t)b * H_ + h) * N_;

    // K half-tiles: [dh-half][key 0..63][32 shorts]; V half-tiles: [key-half][dh 0..63][32 shorts]
    __shared__ short Kb[2][4096];
    __shared__ short Vb[2][4096];
    __shared__ short Pl[4][16 * 40];   // per-wave P tile [qrow][32 keys + pad]

    const short* kbase  = k  + bh * 64;
    const short* vtbase = vT + bh * 64;   // [dh][N] for this (b,h)
    const int* idrow = ids + b * N_;

    // Q A-frags (two dh-chunks of 32)
    bf16x8 aq0, aq1;
    {
        const short* qp = q + (bh + q0 + wave * 16 + m) * 64;
        aq0 = *(const bf16x8*)(qp + quad * 8);
        aq1 = *(const bf16x8*)(qp + 32 + quad * 8);
    }

    const int l4 = lane >> 2, c3 = lane & 3;   // staging lane split: 16 rows x 4 chunks

    auto stage = [&](int t) {
        short* Kd = Kb[t & 1];
        short* Vd = Vb[t & 1];
        const int kt = t * 64;
        const int keyrow = 16 * wave + l4;      // key (for K) / dh (for V), 0..63
#pragma unroll
        for (int hh = 0; hh < 2; ++hh) {        // K: dh-half hh
            const short* gk = kbase + (size_t)(kt + keyrow) * 64 + hh * 32 + c3 * 8;
            __builtin_amdgcn_global_load_lds((gc_ptr)gk,
                (lp_ptr)(Kd + hh * 2048 + 512 * wave + lane * 8), 16, 0, 0);
        }
#pragma unroll
        for (int g = 0; g < 2; ++g) {           // V: key-half g
            const short* gv = vtbase + (size_t)keyrow * N_ + kt + g * 32 + c3 * 8;
            __builtin_amdgcn_global_load_lds((gc_ptr)gv,
                (lp_ptr)(Vd + g * 2048 + 512 * wave + lane * 8), 16, 0, 0);
        }
    };

    float plocal[4] = {0.f, 0.f, 0.f, 0.f};
    f32x4 o[4];
#pragma unroll
    for (int j = 0; j < 4; ++j) o[j] = {0.f, 0.f, 0.f, 0.f};

    short* pw = Pl[wave];

    stage(0);
    for (int t = 0; t < 16; ++t) {
        __syncthreads();                // implicit vmcnt drain publishes tile t
        if (t < 15) stage(t + 1);       // prefetch next tile into other buffer
        const short* Ks = Kb[t & 1];
        const short* Vs = Vb[t & 1];
        const int kt = t * 64;
#pragma unroll
        for (int g = 0; g < 2; ++g) {   // two 32-key subgroups
            const float msk0 = -1e9f * (float)idrow[kt + g * 32 + m];
            const float msk1 = -1e9f * (float)idrow[kt + g * 32 + 16 + m];
            const bf16x8 b00 = *(const bf16x8*)(Ks + (g * 32 + m) * 32 + quad * 8);
            const bf16x8 b01 = *(const bf16x8*)(Ks + 2048 + (g * 32 + m) * 32 + quad * 8);
            const bf16x8 b10 = *(const bf16x8*)(Ks + (g * 32 + 16 + m) * 32 + quad * 8);
            const bf16x8 b11 = *(const bf16x8*)(Ks + 2048 + (g * 32 + 16 + m) * 32 + quad * 8);
            f32x4 s0 = {0.f, 0.f, 0.f, 0.f}, s1 = {0.f, 0.f, 0.f, 0.f};
            s0 = __builtin_amdgcn_mfma_f32_16x16x32_bf16(aq0, b00, s0, 0, 0, 0);
            s0 = __builtin_amdgcn_mfma_f32_16x16x32_bf16(aq1, b01, s0, 0, 0, 0);
            s1 = __builtin_amdgcn_mfma_f32_16x16x32_bf16(aq0, b10, s1, 0, 0, 0);
            s1 = __builtin_amdgcn_mfma_f32_16x16x32_bf16(aq1, b11, s1, 0, 0, 0);
#pragma unroll
            for (int r = 0; r < 4; ++r) {
                const float p0 = __expf((s0[r] + msk0) * 0.125f);
                const float p1 = __expf((s1[r] + msk1) * 0.125f);
                plocal[r] += p0 + p1;
                pw[(quad * 4 + r) * 40 + m]      = f2bf(p0);
                pw[(quad * 4 + r) * 40 + 16 + m] = f2bf(p1);
            }
            // same-wave LDS round-trip (C-layout -> A-layout), no barrier needed
            const bf16x8 pa = *(const bf16x8*)(pw + m * 40 + quad * 8);
#pragma unroll
            for (int j = 0; j < 4; ++j) {
                const bf16x8 bv = *(const bf16x8*)(Vs + g * 2048 + (j * 16 + m) * 32 + quad * 8);
                o[j] = __builtin_amdgcn_mfma_f32_16x16x32_bf16(pa, bv, o[j], 0, 0, 0);
            }
        }
    }

    // single end-of-kernel row-sum reduce, then write O: out[b, n, h*64 + dh]
#pragma unroll
    for (int r = 0; r < 4; ++r) {
        float su = plocal[r];
        su += __shfl_xor(su, 1);
        su += __shfl_xor(su, 2);
        su += __shfl_xor(su, 4);
        su += __shfl_xor(su, 8);
        const float inv = 1.f / su;
        const int n = q0 + wave * 16 + quad * 4 + r;
        short* op = outp + ((size_t)(b * N_ + n)) * D_ + h * 64 + m;
#pragma unroll
        for (int j = 0; j < 4; ++j)
            op[j * 16] = f2bf(o[j][r] * inv);
    }
}

// ---------------------------------------------------------------------------
extern "C" void kernel_launch(void* const* d_in, const int* in_sizes, int n_in,
                              void* d_out, int out_size, void* d_ws, size_t ws_size,
                              hipStream_t stream) {
    const float* x   = (const float*)d_in[0];
    const int*   ids = (const int*)d_in[1];
    const float* n1w = (const float*)d_in[2];
    const float* n1b = (const float*)d_in[3];
    const float* win = (const float*)d_in[4];
    const float* wout= (const float*)d_in[5];
    const float* bout= (const float*)d_in[6];
    const float* n2w = (const float*)d_in[7];
    const float* n2b = (const float*)d_in[8];
    const float* w1  = (const float*)d_in[9];
    const float* b1  = (const float*)d_in[10];
    const float* w2  = (const float*)d_in[11];
    const float* b2  = (const float*)d_in[12];
    float* out = (float*)d_out;

    char* ws = (char*)d_ws;
    size_t off = 0;
    auto alloc = [&](size_t bytes) {
        char* p = ws + off;
        off += (bytes + 255) & ~(size_t)255;
        return p;
    };
    short* wq_b = (short*)alloc((size_t)3 * D_ * D_ * 2);       // proj_in bf16
    short* wo_b = (short*)alloc((size_t)D_ * D_ * 2);           // proj_out bf16
    short* w1_b = (short*)alloc((size_t)FF_ * D_ * 2);          // lin1 bf16
    short* w2_b = (short*)alloc((size_t)D_ * FF_ * 2);          // lin2 bf16
    float* xn32 = (float*)alloc((size_t)TOK_ * D_ * 4);         // LN1 out fp32
    short* xnb  = (short*)alloc((size_t)TOK_ * D_ * 2);         // LN1 out bf16
    short* qkv  = (short*)alloc((size_t)3 * TOK_ * D_ * 2);     // q,k [B,H,N,64]; vT [B,H,64,N]
    float* x2f  = (float*)alloc((size_t)TOK_ * D_ * 4);         // LN2 out fp32
    short* hbuf = (short*)alloc((size_t)TOK_ * FF_ * 2);        // gelu(lin1) bf16
    // aliases (lifetimes disjoint in stream order):
    short* attno = xnb;          // attention output bf16 (xn_bf16 dead after QKV gemm)
    float* x1f   = (float*)qkv;  // x1 fp32 (qkv dead after attention)
    short* x2b   = xnb;          // LN2 bf16 (attno dead after proj_out gemm)

    // 1) weights -> bf16
    cvt_bf16<<<3 * D_ * D_ / 1024, 256, 0, stream>>>(win, wq_b);
    cvt_bf16<<<D_ * D_ / 1024, 256, 0, stream>>>(wout, wo_b);
    cvt_bf16<<<FF_ * D_ / 1024, 256, 0, stream>>>(w1, w1_b);
    cvt_bf16<<<FF_ * D_ / 1024, 256, 0, stream>>>(w2, w2_b);
    // 2) LN1
    ln_kernel<<<TOK_, 256, 0, stream>>>(x, n1w, n1b, xn32, xnb);
    // 3) QKV projection (scatter epilogue, V transposed) — 1D XCD-pinned grid
    gemm_bt<0><<<(3 * D_ / 128) * (TOK_ / 128), 256, 0, stream>>>(
        xnb, wq_b, nullptr, nullptr, qkv, TOK_, 3 * D_, D_);
    // 4) attention — 1D XCD-pinned grid
    attn_kernel<<<(N_ / 64) * H_ * B_, 256, 0, stream>>>(
        qkv, qkv + (size_t)TOK_ * D_, qkv + (size_t)2 * TOK_ * D_, ids, attno);
    // 5) out projection + bias + residual(xn) -> x1 fp32
    gemm_bt<1><<<(D_ / 128) * (TOK_ / 128), 256, 0, stream>>>(
        attno, wo_b, bout, xn32, x1f, TOK_, D_, D_);
    // 6) LN2
    ln_kernel<<<TOK_, 256, 0, stream>>>(x1f, n2w, n2b, x2f, x2b);
    // 7) lin1 + bias + GELU -> h bf16
    gemm_bt<2><<<(FF_ / 128) * (TOK_ / 128), 256, 0, stream>>>(
        x2b, w1_b, b1, nullptr, hbuf, TOK_, FF_, D_);
    // 8) lin2 + bias + residual(x2) -> out fp32
    gemm_bt<1><<<(D_ / 128) * (TOK_ / 128), 256, 0, stream>>>(
        hbuf, w2_b, b2, x2f, out, TOK_, D_, FF_);
}

// Round 7
// 535.147 us; speedup vs baseline: 1.0635x; 1.0289x over previous
//
#include <hip/hip_runtime.h>
#include <hip/hip_bf16.h>

#define B_ 8
#define N_ 1024
#define D_ 1024
#define H_ 16
#define FF_ 4096
#define TOK_ (B_*N_)

typedef __attribute__((ext_vector_type(8))) short bf16x8;
typedef __attribute__((ext_vector_type(4))) float f32x4;

typedef const __attribute__((address_space(1))) void* gc_ptr;
typedef __attribute__((address_space(3))) void* lp_ptr;

// float -> bf16 bits, round-to-nearest-even (values are finite; no NaN path needed)
__device__ __forceinline__ short f2bf(float f) {
    unsigned u = __builtin_bit_cast(unsigned, f);
    u = (u + 0x7FFFu + ((u >> 16) & 1u)) >> 16;
    return (short)u;
}

// ---------------------------------------------------------------------------
// fp32 -> bf16 convert (weights), 4 elements/thread
// ---------------------------------------------------------------------------
__global__ __launch_bounds__(256)
void cvt_bf16(const float* __restrict__ in, short* __restrict__ outp) {
    const size_t i = ((size_t)blockIdx.x * 256 + threadIdx.x) * 4;
    const float4 v = *(const float4*)(in + i);
    short4 o;
    o.x = f2bf(v.x); o.y = f2bf(v.y); o.z = f2bf(v.z); o.w = f2bf(v.w);
    *(short4*)(outp + i) = o;
}

// ---------------------------------------------------------------------------
// LayerNorm over D=1024: one block per row, 256 threads, 4 floats each.
// Writes fp32 (residual path) and bf16 (GEMM input).
// ---------------------------------------------------------------------------
__global__ __launch_bounds__(256)
void ln_kernel(const float* __restrict__ in, const float* __restrict__ w,
               const float* __restrict__ bi, float* __restrict__ o32,
               short* __restrict__ obf) {
    const int row = blockIdx.x;
    const int tid = threadIdx.x;
    const float4 v = ((const float4*)(in + (size_t)row * D_))[tid];
    float s = v.x + v.y + v.z + v.w;
    float q = v.x * v.x + v.y * v.y + v.z * v.z + v.w * v.w;
#pragma unroll
    for (int off = 1; off < 64; off <<= 1) {
        s += __shfl_xor(s, off);
        q += __shfl_xor(q, off);
    }
    __shared__ float ss[4], sq[4];
    const int wave = tid >> 6, lane = tid & 63;
    if (lane == 0) { ss[wave] = s; sq[wave] = q; }
    __syncthreads();
    s = ss[0] + ss[1] + ss[2] + ss[3];
    q = sq[0] + sq[1] + sq[2] + sq[3];
    const float mu = s * (1.f / D_);
    const float var = q * (1.f / D_) - mu * mu;
    const float rs = rsqrtf(var + 1e-5f);
    const float4 wv = ((const float4*)w)[tid];
    const float4 bv = ((const float4*)bi)[tid];
    float4 o;
    o.x = (v.x - mu) * rs * wv.x + bv.x;
    o.y = (v.y - mu) * rs * wv.y + bv.y;
    o.z = (v.z - mu) * rs * wv.z + bv.z;
    o.w = (v.w - mu) * rs * wv.w + bv.w;
    ((float4*)(o32 + (size_t)row * D_))[tid] = o;
    short4 ob;
    ob.x = f2bf(o.x); ob.y = f2bf(o.y); ob.z = f2bf(o.z); ob.w = f2bf(o.w);
    *(short4*)(obf + (size_t)row * D_ + tid * 4) = ob;
}

// ---------------------------------------------------------------------------
// GEMM: C[M,Nc] = A[M,K] @ Bw[Nc,K]^T  (both bf16, K-contiguous)
// 128x128 tile, BK=32, 4 waves each owning 64x64 (4x4 of 16x16x32 MFMA).
// Double-buffered global_load_lds staging, one barrier/iter, XCD-pinned
// tile map (xcd = lin&7), and v4: XOR CHUNK SWIZZLE — LDS row r stores
// global 16B-chunk (c ^ ((r>>1)&3)) at slot c, so frag ds_read_b128 banks
// spread to the floor (2 dwords/bank/phase). Pure permutation, staged via
// permuted global source (LDS dest of global_load_lds is fixed).
// MODE 0: scatter q,k -> [B,H,N,64]; v -> TRANSPOSED [B,H,64,N]
// MODE 1: out_f32 = acc + bias[col] + res[row,col]
// MODE 2: out_bf16 = gelu_exact(acc + bias[col])
// ---------------------------------------------------------------------------
template<int MODE>
__global__ __launch_bounds__(256, 2)
void gemm_bt(const short* __restrict__ A, const short* __restrict__ Bw,
             const float* __restrict__ bias, const float* __restrict__ res,
             void* __restrict__ outp, int M, int Nc, int K) {
    const int tid  = threadIdx.x;
    const int wave = tid >> 6;
    const int lane = tid & 63;
    const int m16  = lane & 15;
    const int quad = lane >> 4;
    const int wrow = (wave >> 1) * 64;
    const int wcol = (wave & 1) * 64;

    // XCD-pinned decode (requires M/128 % 8 == 0 — true for all calls: gy=64)
    const int gy = M >> 7;             // row-tiles
    const int rowsPerX = gy >> 3;      // row-tiles per XCD
    const int lin  = blockIdx.x;
    const int xcd  = lin & 7;
    const int loc  = lin >> 3;
    const int rowL = loc % rowsPerX;
    const int colT = loc / rowsPerX;
    const int rowBase = (rowL * 8 + xcd) * 128;
    const int colBase = colT * 128;

    __shared__ short sA[2][128 * 32];
    __shared__ short sB[2][128 * 32];

    f32x4 acc[4][4];
#pragma unroll
    for (int i = 0; i < 4; ++i)
#pragma unroll
        for (int j = 0; j < 4; ++j)
            acc[i][j] = {0.f, 0.f, 0.f, 0.f};

    const int r16 = lane >> 2;              // row within 16-row staging group
    const int c4  = lane & 3;               // LDS slot within 64B row
    const int csw = c4 ^ ((r16 >> 1) & 3);  // swizzled global chunk for this slot

    auto stage = [&](int t) {
        const int kt = t * 32;
        short* dA = sA[t & 1];
        short* dB = sB[t & 1];
#pragma unroll
        for (int rep = 0; rep < 2; ++rep) {
            const int tr = rep * 64 + wave * 16;
            const short* ga = A  + (size_t)(rowBase + tr + r16) * K + kt + csw * 8;
            const short* gb = Bw + (size_t)(colBase + tr + r16) * K + kt + csw * 8;
            __builtin_amdgcn_global_load_lds((gc_ptr)ga, (lp_ptr)(dA + tr * 32), 16, 0, 0);
            __builtin_amdgcn_global_load_lds((gc_ptr)gb, (lp_ptr)(dB + tr * 32), 16, 0, 0);
        }
    };

    const int qsw = (quad ^ ((m16 >> 1) & 3)) * 8;  // swizzled frag-read slot

    const int T = K >> 5;
    stage(0);
    for (int t = 0; t < T; ++t) {
        __syncthreads();             // implicit vmcnt drain publishes tile t
        if (t + 1 < T) stage(t + 1); // prefetch next tile into other buffer
        const short* cA = sA[t & 1];
        const short* cB = sB[t & 1];

        bf16x8 af[4], bfr[4];
#pragma unroll
        for (int i = 0; i < 4; ++i)
            af[i] = *(const bf16x8*)(cA + (wrow + i * 16 + m16) * 32 + qsw);
#pragma unroll
        for (int j = 0; j < 4; ++j)
            bfr[j] = *(const bf16x8*)(cB + (wcol + j * 16 + m16) * 32 + qsw);
#pragma unroll
        for (int i = 0; i < 4; ++i)
#pragma unroll
            for (int j = 0; j < 4; ++j)
                acc[i][j] = __builtin_amdgcn_mfma_f32_16x16x32_bf16(af[i], bfr[j], acc[i][j], 0, 0, 0);
    }

    // epilogue: C/D layout col = lane&15, row = quad*4 + r  (m89-verified)
#pragma unroll
    for (int i = 0; i < 4; ++i) {
#pragma unroll
        for (int j = 0; j < 4; ++j) {
            const int col = colBase + wcol + j * 16 + m16;
#pragma unroll
            for (int r = 0; r < 4; ++r) {
                const int row = rowBase + wrow + i * 16 + quad * 4 + r;
                const float val = acc[i][j][r];
                if (MODE == 0) {
                    const int ci = col >> 10, hh = (col >> 6) & 15, dd = col & 63;
                    const int bb = row >> 10, nn = row & 1023;
                    size_t idx;
                    if (ci == 2)   // V transposed: [b,h,dh,N]
                        idx = (size_t)2 * ((size_t)TOK_ * 1024) +
                              ((size_t)((bb * H_ + hh) * 64 + dd)) * N_ + nn;
                    else
                        idx = (size_t)ci * ((size_t)TOK_ * 1024) +
                              ((size_t)((bb * H_ + hh) * N_ + nn)) * 64 + dd;
                    ((short*)outp)[idx] = f2bf(val);
                } else if (MODE == 1) {
                    ((float*)outp)[(size_t)row * Nc + col] =
                        val + bias[col] + res[(size_t)row * Nc + col];
                } else {
                    const float t = val + bias[col];
                    const float g = 0.5f * t * (1.f + erff(t * 0.70710678118654752f));
                    ((short*)outp)[(size_t)row * Nc + col] = f2bf(g);
                }
            }
        }
    }
}

// ---------------------------------------------------------------------------
// Flash attention v5: 1D grid, XCD-pinned (lin%8 = head%8). Block = 64
// q-rows, 4 waves x 16 rows. KT=64 double-buffered K/V via global_load_lds,
// one barrier/tile, no-max softmax. Same XOR chunk swizzle as gemm_bt on
// K/V staging + frag reads.
// ---------------------------------------------------------------------------
__global__ __launch_bounds__(256, 4)
void attn_kernel(const short* __restrict__ q, const short* __restrict__ k,
                 const short* __restrict__ vT, const int* __restrict__ ids,
                 short* __restrict__ outp) {
    const int tid  = threadIdx.x;
    const int wave = tid >> 6;
    const int lane = tid & 63;
    const int m    = lane & 15;
    const int quad = lane >> 4;
    const int lin  = blockIdx.x;
    const int qb   = lin >> 7;          // 16 q-blocks
    const int bhid = lin & 127;         // b*16+h
    const int b  = bhid >> 4;
    const int h  = bhid & 15;
    const int q0 = qb * 64;
    const size_t bh = ((size_t)b * H_ + h) * N_;

    // K half-tiles: [dh-half][key 0..63][32 shorts]; V half-tiles: [key-half][dh 0..63][32 shorts]
    __shared__ short Kb[2][4096];
    __shared__ short Vb[2][4096];
    __shared__ short Pl[4][16 * 40];   // per-wave P tile [qrow][32 keys + pad]

    const short* kbase  = k  + bh * 64;
    const short* vtbase = vT + bh * 64;   // [dh][N] for this (b,h)
    const int* idrow = ids + b * N_;

    // Q A-frags (two dh-chunks of 32)
    bf16x8 aq0, aq1;
    {
        const short* qp = q + (bh + q0 + wave * 16 + m) * 64;
        aq0 = *(const bf16x8*)(qp + quad * 8);
        aq1 = *(const bf16x8*)(qp + 32 + quad * 8);
    }

    const int l4 = lane >> 2, c3 = lane & 3;     // staging: 16 rows x 4 slots
    const int csw = c3 ^ ((l4 >> 1) & 3);        // swizzled global chunk

    auto stage = [&](int t) {
        short* Kd = Kb[t & 1];
        short* Vd = Vb[t & 1];
        const int kt = t * 64;
        const int keyrow = 16 * wave + l4;      // key (for K) / dh (for V), 0..63
#pragma unroll
        for (int hh = 0; hh < 2; ++hh) {        // K: dh-half hh
            const short* gk = kbase + (size_t)(kt + keyrow) * 64 + hh * 32 + csw * 8;
            __builtin_amdgcn_global_load_lds((gc_ptr)gk,
                (lp_ptr)(Kd + hh * 2048 + 512 * wave + lane * 8), 16, 0, 0);
        }
#pragma unroll
        for (int g = 0; g < 2; ++g) {           // V: key-half g
            const short* gv = vtbase + (size_t)keyrow * N_ + kt + g * 32 + csw * 8;
            __builtin_amdgcn_global_load_lds((gc_ptr)gv,
                (lp_ptr)(Vd + g * 2048 + 512 * wave + lane * 8), 16, 0, 0);
        }
    };

    float plocal[4] = {0.f, 0.f, 0.f, 0.f};
    f32x4 o[4];
#pragma unroll
    for (int j = 0; j < 4; ++j) o[j] = {0.f, 0.f, 0.f, 0.f};

    short* pw = Pl[wave];
    const int qsw = (quad ^ ((m >> 1) & 3)) * 8;  // swizzled frag-read slot

    stage(0);
    for (int t = 0; t < 16; ++t) {
        __syncthreads();                // implicit vmcnt drain publishes tile t
        if (t < 15) stage(t + 1);       // prefetch next tile into other buffer
        const short* Ks = Kb[t & 1];
        const short* Vs = Vb[t & 1];
        const int kt = t * 64;
#pragma unroll
        for (int g = 0; g < 2; ++g) {   // two 32-key subgroups
            const float msk0 = -1e9f * (float)idrow[kt + g * 32 + m];
            const float msk1 = -1e9f * (float)idrow[kt + g * 32 + 16 + m];
            const bf16x8 b00 = *(const bf16x8*)(Ks + (g * 32 + m) * 32 + qsw);
            const bf16x8 b01 = *(const bf16x8*)(Ks + 2048 + (g * 32 + m) * 32 + qsw);
            const bf16x8 b10 = *(const bf16x8*)(Ks + (g * 32 + 16 + m) * 32 + qsw);
            const bf16x8 b11 = *(const bf16x8*)(Ks + 2048 + (g * 32 + 16 + m) * 32 + qsw);
            f32x4 s0 = {0.f, 0.f, 0.f, 0.f}, s1 = {0.f, 0.f, 0.f, 0.f};
            s0 = __builtin_amdgcn_mfma_f32_16x16x32_bf16(aq0, b00, s0, 0, 0, 0);
            s0 = __builtin_amdgcn_mfma_f32_16x16x32_bf16(aq1, b01, s0, 0, 0, 0);
            s1 = __builtin_amdgcn_mfma_f32_16x16x32_bf16(aq0, b10, s1, 0, 0, 0);
            s1 = __builtin_amdgcn_mfma_f32_16x16x32_bf16(aq1, b11, s1, 0, 0, 0);
#pragma unroll
            for (int r = 0; r < 4; ++r) {
                const float p0 = __expf((s0[r] + msk0) * 0.125f);
                const float p1 = __expf((s1[r] + msk1) * 0.125f);
                plocal[r] += p0 + p1;
                pw[(quad * 4 + r) * 40 + m]      = f2bf(p0);
                pw[(quad * 4 + r) * 40 + 16 + m] = f2bf(p1);
            }
            // same-wave LDS round-trip (C-layout -> A-layout), no barrier needed
            const bf16x8 pa = *(const bf16x8*)(pw + m * 40 + quad * 8);
#pragma unroll
            for (int j = 0; j < 4; ++j) {
                const bf16x8 bv = *(const bf16x8*)(Vs + g * 2048 + (j * 16 + m) * 32 + qsw);
                o[j] = __builtin_amdgcn_mfma_f32_16x16x32_bf16(pa, bv, o[j], 0, 0, 0);
            }
        }
    }

    // single end-of-kernel row-sum reduce, then write O: out[b, n, h*64 + dh]
#pragma unroll
    for (int r = 0; r < 4; ++r) {
        float su = plocal[r];
        su += __shfl_xor(su, 1);
        su += __shfl_xor(su, 2);
        su += __shfl_xor(su, 4);
        su += __shfl_xor(su, 8);
        const float inv = 1.f / su;
        const int n = q0 + wave * 16 + quad * 4 + r;
        short* op = outp + ((size_t)(b * N_ + n)) * D_ + h * 64 + m;
#pragma unroll
        for (int j = 0; j < 4; ++j)
            op[j * 16] = f2bf(o[j][r] * inv);
    }
}

// ---------------------------------------------------------------------------
extern "C" void kernel_launch(void* const* d_in, const int* in_sizes, int n_in,
                              void* d_out, int out_size, void* d_ws, size_t ws_size,
                              hipStream_t stream) {
    const float* x   = (const float*)d_in[0];
    const int*   ids = (const int*)d_in[1];
    const float* n1w = (const float*)d_in[2];
    const float* n1b = (const float*)d_in[3];
    const float* win = (const float*)d_in[4];
    const float* wout= (const float*)d_in[5];
    const float* bout= (const float*)d_in[6];
    const float* n2w = (const float*)d_in[7];
    const float* n2b = (const float*)d_in[8];
    const float* w1  = (const float*)d_in[9];
    const float* b1  = (const float*)d_in[10];
    const float* w2  = (const float*)d_in[11];
    const float* b2  = (const float*)d_in[12];
    float* out = (float*)d_out;

    char* ws = (char*)d_ws;
    size_t off = 0;
    auto alloc = [&](size_t bytes) {
        char* p = ws + off;
        off += (bytes + 255) & ~(size_t)255;
        return p;
    };
    short* wq_b = (short*)alloc((size_t)3 * D_ * D_ * 2);       // proj_in bf16
    short* wo_b = (short*)alloc((size_t)D_ * D_ * 2);           // proj_out bf16
    short* w1_b = (short*)alloc((size_t)FF_ * D_ * 2);          // lin1 bf16
    short* w2_b = (short*)alloc((size_t)D_ * FF_ * 2);          // lin2 bf16
    float* xn32 = (float*)alloc((size_t)TOK_ * D_ * 4);         // LN1 out fp32
    short* xnb  = (short*)alloc((size_t)TOK_ * D_ * 2);         // LN1 out bf16
    short* qkv  = (short*)alloc((size_t)3 * TOK_ * D_ * 2);     // q,k [B,H,N,64]; vT [B,H,64,N]
    float* x2f  = (float*)alloc((size_t)TOK_ * D_ * 4);         // LN2 out fp32
    short* hbuf = (short*)alloc((size_t)TOK_ * FF_ * 2);        // gelu(lin1) bf16
    // aliases (lifetimes disjoint in stream order):
    short* attno = xnb;          // attention output bf16 (xn_bf16 dead after QKV gemm)
    float* x1f   = (float*)qkv;  // x1 fp32 (qkv dead after attention)
    short* x2b   = xnb;          // LN2 bf16 (attno dead after proj_out gemm)

    // 1) weights -> bf16
    cvt_bf16<<<3 * D_ * D_ / 1024, 256, 0, stream>>>(win, wq_b);
    cvt_bf16<<<D_ * D_ / 1024, 256, 0, stream>>>(wout, wo_b);
    cvt_bf16<<<FF_ * D_ / 1024, 256, 0, stream>>>(w1, w1_b);
    cvt_bf16<<<FF_ * D_ / 1024, 256, 0, stream>>>(w2, w2_b);
    // 2) LN1
    ln_kernel<<<TOK_, 256, 0, stream>>>(x, n1w, n1b, xn32, xnb);
    // 3) QKV projection (scatter epilogue, V transposed) — 1D XCD-pinned grid
    gemm_bt<0><<<(3 * D_ / 128) * (TOK_ / 128), 256, 0, stream>>>(
        xnb, wq_b, nullptr, nullptr, qkv, TOK_, 3 * D_, D_);
    // 4) attention — 1D XCD-pinned grid
    attn_kernel<<<(N_ / 64) * H_ * B_, 256, 0, stream>>>(
        qkv, qkv + (size_t)TOK_ * D_, qkv + (size_t)2 * TOK_ * D_, ids, attno);
    // 5) out projection + bias + residual(xn) -> x1 fp32
    gemm_bt<1><<<(D_ / 128) * (TOK_ / 128), 256, 0, stream>>>(
        attno, wo_b, bout, xn32, x1f, TOK_, D_, D_);
    // 6) LN2
    ln_kernel<<<TOK_, 256, 0, stream>>>(x1f, n2w, n2b, x2f, x2b);
    // 7) lin1 + bias + GELU -> h bf16
    gemm_bt<2><<<(FF_ / 128) * (TOK_ / 128), 256, 0, stream>>>(
        x2b, w1_b, b1, nullptr, hbuf, TOK_, FF_, D_);
    // 8) lin2 + bias + residual(x2) -> out fp32
    gemm_bt<1><<<(D_ / 128) * (TOK_ / 128), 256, 0, stream>>>(
        hbuf, w2_b, b2, x2f, out, TOK_, D_, FF_);
}